// Round 15
// baseline (364.218 us; speedup 1.0000x reference)
//
#include <hip/hip_runtime.h>

#define S_LEN 2048
#define NHEAD 24
#define CDIM 64
#define DDIM 256

typedef _Float16 f16x8 __attribute__((ext_vector_type(8)));
typedef float f32x4 __attribute__((ext_vector_type(4)));

__device__ __forceinline__ ushort f2h(float f) {
    _Float16 h = (_Float16)f;
    return __builtin_bit_cast(ushort, h);
}
__device__ __forceinline__ uint pkh(float a, float b) {
    auto v = __builtin_amdgcn_cvt_pkrtz(a, b);   // __fp16 ext_vector(2)
    return __builtin_bit_cast(uint, v);
}

// pack 8 consecutive f32 -> 8 f16 (register ops only)
__device__ __forceinline__ int4 cvt8(const float* __restrict__ p) {
    float4 a = *(const float4*)p;
    float4 b = *(const float4*)(p + 4);
    f16x8 h;
    h[0] = (_Float16)a.x; h[1] = (_Float16)a.y;
    h[2] = (_Float16)a.z; h[3] = (_Float16)a.w;
    h[4] = (_Float16)b.x; h[5] = (_Float16)b.y;
    h[6] = (_Float16)b.z; h[7] = (_Float16)b.w;
    return __builtin_bit_cast(int4, h);
}

// C = A (MxK,f32) @ W^T (NxK,f32) + bias, MFMA f16 16x16x32, 64x64 tile, 4 waves.
__global__ __launch_bounds__(256) void gemm_bt_kernel(
    const float* __restrict__ A, const float* __restrict__ W,
    const float* __restrict__ bias, int M, int N, int K,
    int mode, int hbase,
    ushort* __restrict__ Kbuf, ushort* __restrict__ Qbuf, ushort* __restrict__ Vt)
{
    __shared__ ushort Asub[64 * 40];
    __shared__ ushort Wsub[64 * 40];
    const int tid = threadIdx.x;
    const int wave = tid >> 6, lane = tid & 63;
    const int g = lane >> 4, c = lane & 15;
    const int m0 = blockIdx.y * 64, n0 = blockIdx.x * 64;
    const int srow = tid >> 2;
    const int skk = (tid & 3) * 8;

    f32x4 acc[4] = {f32x4{0,0,0,0}, f32x4{0,0,0,0}, f32x4{0,0,0,0}, f32x4{0,0,0,0}};

    for (int k0 = 0; k0 < K; k0 += 32) {
        __syncthreads();
        *(int4*)&Asub[srow * 40 + skk] = cvt8(&A[(m0 + srow) * K + k0 + skk]);
        *(int4*)&Wsub[srow * 40 + skk] = cvt8(&W[(n0 + srow) * K + k0 + skk]);
        __syncthreads();
        f16x8 af = *(const f16x8*)&Asub[(wave * 16 + c) * 40 + g * 8];
#pragma unroll
        for (int t = 0; t < 4; t++) {
            f16x8 bf = *(const f16x8*)&Wsub[(t * 16 + c) * 40 + g * 8];
            acc[t] = __builtin_amdgcn_mfma_f32_16x16x32_f16(af, bf, acc[t], 0, 0, 0);
        }
    }

#pragma unroll
    for (int t = 0; t < 4; t++) {
        int n = n0 + t * 16 + c;
        float bv = bias[n];
#pragma unroll
        for (int r = 0; r < 4; r++) {
            int m = m0 + wave * 16 + g * 4 + r;
            ushort u = f2h(acc[t][r] + bv);
            if (mode == 0) {
                int h = hbase + (n >> 7);
                int cc = n & 127;
                if (cc < 64) Kbuf[(h * S_LEN + m) * CDIM + cc] = u;
                else         Qbuf[(h * S_LEN + m) * CDIM + cc - 64] = u;
            } else {
                int h = n >> 8;
                int d = n & 255;
                Vt[(h * DDIM + d) * S_LEN + m] = u;
            }
        }
    }
}

// rot projection: K=4, no bias, f32 math.
__global__ __launch_bounds__(256) void rot_proj_kernel(
    const float* __restrict__ rot, const float* __restrict__ Wrot,
    ushort* __restrict__ Kbuf, ushort* __restrict__ Qbuf)
{
    int idx = blockIdx.x * 256 + threadIdx.x;
    int i = idx >> 10, n = idx & 1023;
    float4 r = *(const float4*)&rot[i * 4];
    float4 w = *(const float4*)&Wrot[n * 4];
    float v = r.x * w.x + r.y * w.y + r.z * w.z + r.w * w.w;
    int h = 16 + (n >> 7), cc = n & 127;
    ushort u = f2h(v);
    if (cc < 64) Kbuf[(h * S_LEN + i) * CDIM + cc] = u;
    else         Qbuf[(h * S_LEN + i) * CDIM + cc - 64] = u;
}

__global__ __launch_bounds__(256) void zero_kernel(float* __restrict__ p) {
    p[blockIdx.x * 256 + threadIdx.x] = 0.f;
}

// Flash attention per (head, 64-row i-tile). 4 waves, d-split PV.
// S^T orientation: QK computes S^T (A=Q, B=K) so each lane's 16 scores all
// belong to ONE row i=c -> softmax state is scalar per lane, cross-lane
// reduction is 2 shfl rounds (offsets 16,32), and P-writes are j-contiguous
// b64 stores (cvt_pkrtz pairs). PV identical to R13 (A=P, B=V regs).
// Double-buffered Q + P, one __syncthreads per iter. Writes directly to out.
__global__ __launch_bounds__(256, 4) void flash_kernel(
    const ushort* __restrict__ Kbuf, const ushort* __restrict__ Qbuf,
    const ushort* __restrict__ Vt, float* __restrict__ out)
{
    __shared__ ushort Qlds[2][64 * 72];   // [buf][j'][c], stride 72
    __shared__ ushort Plds[2][64 * 72];   // [buf][i'][j'], stride 72
    __shared__ float  Alds[2][64];        // [buf][i'] alpha / final 1/l

    const int tid = threadIdx.x;
    const int wave = tid >> 6, lane = tid & 63;
    const int g = lane >> 4, c = lane & 15;
    const int h = blockIdx.y;
    const int i0 = blockIdx.x * 64;
    const float SC = 0.51006973f;         // log2(e)/sqrt(8)

    // K b-frags for wave's 16 rows (i = i0 + wave*16 + c)
    const ushort* Krow = &Kbuf[(h * S_LEN + i0 + wave * 16 + c) * CDIM + g * 8];
    f16x8 ka0 = *(const f16x8*)Krow;
    f16x8 ka1 = *(const f16x8*)(Krow + 32);

    // V base for this wave's d-slice
    const ushort* Vbase = &Vt[(h * DDIM + wave * 64 + c) * S_LEN + g * 8];

    // Q staging indices
    const int qi0 = tid, qi1 = tid + 256;
    const int qr0 = qi0 >> 3, qc0 = (qi0 & 7) * 8;
    const int qr1 = qi1 >> 3, qc1 = (qi1 & 7) * 8;

    *(int4*)&Qlds[0][qr0 * 72 + qc0] =
        *(const int4*)&Qbuf[(h * S_LEN + qr0) * CDIM + qc0];
    *(int4*)&Qlds[0][qr1 * 72 + qc1] =
        *(const int4*)&Qbuf[(h * S_LEN + qr1) * CDIM + qc1];
    __syncthreads();

    f32x4 acc[16];   // [b*4+t]: rows b*16+g*4+r, cols wave*64+t*16+c
#pragma unroll
    for (int t = 0; t < 16; t++) acc[t] = f32x4{0, 0, 0, 0};
    float mrow = -1e30f, lrow = 0.f;      // state for row i = c (per lane)

    for (int j0 = 0; j0 < S_LEN; j0 += 64) {
        const int cur = (j0 >> 6) & 1, nxt = cur ^ 1;

        // prefetch next Q tile into regs (OOB reads land in Vt -> safe)
        const int jn = j0 + 64;
        int4 qn0 = *(const int4*)&Qbuf[(h * S_LEN + jn + qr0) * CDIM + qc0];
        int4 qn1 = *(const int4*)&Qbuf[(h * S_LEN + jn + qr1) * CDIM + qc1];

        // V fragments for THIS iter
        f16x8 vf0[4], vf1[4];
#pragma unroll
        for (int t = 0; t < 4; t++) {
            const ushort* Vr = Vbase + (t * 16) * S_LEN + j0;
            vf0[t] = *(const f16x8*)Vr;
            vf1[t] = *(const f16x8*)(Vr + 32);
        }

        // QK (S^T): lane holds S[i=c][j = jc*16 + g*4 + r]
        f32x4 Sf[4];
#pragma unroll
        for (int jc = 0; jc < 4; jc++) {
            const ushort* Qr = &Qlds[cur][(jc * 16 + c) * 72 + g * 8];
            f16x8 qb0 = *(const f16x8*)Qr;
            f16x8 qb1 = *(const f16x8*)(Qr + 32);
            f32x4 s = {0, 0, 0, 0};
            s = __builtin_amdgcn_mfma_f32_16x16x32_f16(qb0, ka0, s, 0, 0, 0);
            s = __builtin_amdgcn_mfma_f32_16x16x32_f16(qb1, ka1, s, 0, 0, 0);
            Sf[jc] = s * SC;              // exp2 domain
        }

        // softmax for row i=c: reduce own 16 values, then across g (lanes c,c+16,...)
        float nm = -1e30f;
#pragma unroll
        for (int jc = 0; jc < 4; jc++)
            nm = fmaxf(nm, fmaxf(fmaxf(Sf[jc][0], Sf[jc][1]),
                                 fmaxf(Sf[jc][2], Sf[jc][3])));
        nm = fmaxf(nm, __shfl_xor(nm, 16));
        nm = fmaxf(nm, __shfl_xor(nm, 32));
        nm = fmaxf(nm, mrow);
        float alpha = exp2f(mrow - nm);

        float rs = 0.f;
#pragma unroll
        for (int jc = 0; jc < 4; jc++) {
            float p0 = exp2f(Sf[jc][0] - nm);
            float p1 = exp2f(Sf[jc][1] - nm);
            float p2 = exp2f(Sf[jc][2] - nm);
            float p3 = exp2f(Sf[jc][3] - nm);
            rs += (p0 + p1) + (p2 + p3);
            uint2 w;
            w.x = pkh(p0, p1);
            w.y = pkh(p2, p3);
            *(uint2*)&Plds[cur][(wave * 16 + c) * 72 + jc * 16 + g * 4] = w;
        }
        rs += __shfl_xor(rs, 16);
        rs += __shfl_xor(rs, 32);
        lrow = lrow * alpha + rs;
        mrow = nm;
        if (g == 0) Alds[cur][wave * 16 + c] = alpha;

        // stage next Q tile
        *(int4*)&Qlds[nxt][qr0 * 72 + qc0] = qn0;
        *(int4*)&Qlds[nxt][qr1 * 72 + qc1] = qn1;

        __syncthreads();   // P + alpha visible; Q[nxt] staged

        // rescale acc by per-row alpha (broadcast reads, vector mul)
#pragma unroll
        for (int b = 0; b < 4; b++) {
            f32x4 ab = *(const f32x4*)&Alds[cur][b * 16 + g * 4];
#pragma unroll
            for (int t = 0; t < 4; t++) acc[b * 4 + t] *= ab;
        }

        // PV: P(64x64) @ V(64x64-slice)
#pragma unroll
        for (int b = 0; b < 4; b++) {
            const ushort* Pr = &Plds[cur][(b * 16 + c) * 72 + g * 8];
            f16x8 pa0 = *(const f16x8*)Pr;
            f16x8 pa1 = *(const f16x8*)(Pr + 32);
#pragma unroll
            for (int t = 0; t < 4; t++) {
                acc[b * 4 + t] = __builtin_amdgcn_mfma_f32_16x16x32_f16(pa0, vf0[t], acc[b * 4 + t], 0, 0, 0);
                acc[b * 4 + t] = __builtin_amdgcn_mfma_f32_16x16x32_f16(pa1, vf1[t], acc[b * 4 + t], 0, 0, 0);
            }
        }
    }

    // publish 1/lrow, then scale + accumulate directly into out
    __syncthreads();
    if (g == 0) Alds[0][wave * 16 + c] = 1.0f / lrow;
    __syncthreads();
#pragma unroll
    for (int b = 0; b < 4; b++) {
        f32x4 lb = *(const f32x4*)&Alds[0][b * 16 + g * 4];
#pragma unroll
        for (int t = 0; t < 4; t++)
#pragma unroll
            for (int r = 0; r < 4; r++) {
                int i = i0 + b * 16 + g * 4 + r;
                int d = wave * 64 + t * 16 + c;
                atomicAdd(&out[i * DDIM + d], acc[b * 4 + t][r] * lb[r]);
            }
    }
}

extern "C" void kernel_launch(void* const* d_in, const int* in_sizes, int n_in,
                              void* d_out, int out_size, void* d_ws, size_t ws_size,
                              hipStream_t stream) {
    const float *nodes = 0, *aux = 0, *rot = 0, *W_nodes = 0, *b_nodes = 0,
                *W_aux = 0, *b_aux = 0, *W_rot = 0, *W_val = 0, *b_val = 0;
    int i1024[2] = {-1, -1};
    int n1024 = 0;
    for (int i = 0; i < n_in; ++i) {
        const float* p = (const float*)d_in[i];
        switch (in_sizes[i]) {
            case 524288:  nodes   = p; break;
            case 131072:  aux     = p; break;
            case 8192:    rot     = p; break;
            case 262144:  W_nodes = p; break;
            case 65536:   W_aux   = p; break;
            case 4096:    W_rot   = p; break;
            case 1572864: W_val   = p; break;
            case 6144:    b_val   = p; break;
            case 1024:    if (n1024 < 2) i1024[n1024] = i; n1024++; break;
            default: break;
        }
    }
    if (n1024 == 2) {
        b_nodes = (const float*)d_in[i1024[0]];
        b_aux   = (const float*)d_in[i1024[1]];
    }
    if (!nodes || !aux || !rot || !W_nodes || !b_nodes || !W_aux || !b_aux ||
        !W_rot || !W_val || !b_val) {
        nodes   = (const float*)d_in[0];
        aux     = (const float*)d_in[1];
        rot     = (const float*)d_in[2];
        W_nodes = (const float*)d_in[3];
        b_nodes = (const float*)d_in[4];
        W_aux   = (const float*)d_in[5];
        b_aux   = (const float*)d_in[6];
        W_rot   = (const float*)d_in[7];
        W_val   = (const float*)d_in[8];
        b_val   = (const float*)d_in[9];
    }
    float* out = (float*)d_out;

    // ws layout: (unused f32 pad 2MB) | K f16 | Q f16 | Vt f16
    float*  Opad = (float*)d_ws;
    ushort* Kbuf = (ushort*)(Opad + S_LEN * DDIM);
    ushort* Qbuf = Kbuf + NHEAD * S_LEN * CDIM;
    ushort* Vt   = Qbuf + NHEAD * S_LEN * CDIM;

    dim3 blk(256);
    zero_kernel<<<dim3(S_LEN * DDIM / 256), blk, 0, stream>>>(out);
    gemm_bt_kernel<<<dim3(16, 32), blk, 0, stream>>>(nodes, W_nodes, b_nodes,
        2048, 1024, 256, 0, 0, Kbuf, Qbuf, nullptr);
    gemm_bt_kernel<<<dim3(16, 32), blk, 0, stream>>>(aux, W_aux, b_aux,
        2048, 1024, 64, 0, 8, Kbuf, Qbuf, nullptr);
    rot_proj_kernel<<<dim3(8192), blk, 0, stream>>>(rot, W_rot, Kbuf, Qbuf);
    gemm_bt_kernel<<<dim3(96, 32), blk, 0, stream>>>(nodes, W_val, b_val,
        2048, 6144, 256, 1, 0, nullptr, nullptr, Vt);
    flash_kernel<<<dim3(32, NHEAD), blk, 0, stream>>>(Kbuf, Qbuf, Vt, out);
}

// Round 16
// 271.960 us; speedup vs baseline: 1.3392x; 1.3392x over previous
//
#include <hip/hip_runtime.h>

#define S_LEN 2048
#define NHEAD 24
#define CDIM 64
#define DDIM 256

typedef _Float16 f16x8 __attribute__((ext_vector_type(8)));
typedef float f32x4 __attribute__((ext_vector_type(4)));

__device__ __forceinline__ ushort f2h(float f) {
    _Float16 h = (_Float16)f;
    return __builtin_bit_cast(ushort, h);
}
__device__ __forceinline__ uint pkh(float a, float b) {
    auto v = __builtin_amdgcn_cvt_pkrtz(a, b);   // __fp16 ext_vector(2)
    return __builtin_bit_cast(uint, v);
}

// pack 8 consecutive f32 -> 8 f16 (register ops only)
__device__ __forceinline__ int4 cvt8(const float* __restrict__ p) {
    float4 a = *(const float4*)p;
    float4 b = *(const float4*)(p + 4);
    f16x8 h;
    h[0] = (_Float16)a.x; h[1] = (_Float16)a.y;
    h[2] = (_Float16)a.z; h[3] = (_Float16)a.w;
    h[4] = (_Float16)b.x; h[5] = (_Float16)b.y;
    h[6] = (_Float16)b.z; h[7] = (_Float16)b.w;
    return __builtin_bit_cast(int4, h);
}

// C = A (MxK,f32) @ W^T (NxK,f32) + bias, MFMA f16 16x16x32, 64x64 tile, 4 waves.
__global__ __launch_bounds__(256) void gemm_bt_kernel(
    const float* __restrict__ A, const float* __restrict__ W,
    const float* __restrict__ bias, int M, int N, int K,
    int mode, int hbase,
    ushort* __restrict__ Kbuf, ushort* __restrict__ Qbuf, ushort* __restrict__ Vt)
{
    __shared__ ushort Asub[64 * 40];
    __shared__ ushort Wsub[64 * 40];
    const int tid = threadIdx.x;
    const int wave = tid >> 6, lane = tid & 63;
    const int g = lane >> 4, c = lane & 15;
    const int m0 = blockIdx.y * 64, n0 = blockIdx.x * 64;
    const int srow = tid >> 2;
    const int skk = (tid & 3) * 8;

    f32x4 acc[4] = {f32x4{0,0,0,0}, f32x4{0,0,0,0}, f32x4{0,0,0,0}, f32x4{0,0,0,0}};

    for (int k0 = 0; k0 < K; k0 += 32) {
        __syncthreads();
        *(int4*)&Asub[srow * 40 + skk] = cvt8(&A[(m0 + srow) * K + k0 + skk]);
        *(int4*)&Wsub[srow * 40 + skk] = cvt8(&W[(n0 + srow) * K + k0 + skk]);
        __syncthreads();
        f16x8 af = *(const f16x8*)&Asub[(wave * 16 + c) * 40 + g * 8];
#pragma unroll
        for (int t = 0; t < 4; t++) {
            f16x8 bf = *(const f16x8*)&Wsub[(t * 16 + c) * 40 + g * 8];
            acc[t] = __builtin_amdgcn_mfma_f32_16x16x32_f16(af, bf, acc[t], 0, 0, 0);
        }
    }

#pragma unroll
    for (int t = 0; t < 4; t++) {
        int n = n0 + t * 16 + c;
        float bv = bias[n];
#pragma unroll
        for (int r = 0; r < 4; r++) {
            int m = m0 + wave * 16 + g * 4 + r;
            ushort u = f2h(acc[t][r] + bv);
            if (mode == 0) {
                int h = hbase + (n >> 7);
                int cc = n & 127;
                if (cc < 64) Kbuf[(h * S_LEN + m) * CDIM + cc] = u;
                else         Qbuf[(h * S_LEN + m) * CDIM + cc - 64] = u;
            } else {
                int h = n >> 8;
                int d = n & 255;
                Vt[(h * DDIM + d) * S_LEN + m] = u;
            }
        }
    }
}

// rot projection: K=4, no bias, f32 math.
__global__ __launch_bounds__(256) void rot_proj_kernel(
    const float* __restrict__ rot, const float* __restrict__ Wrot,
    ushort* __restrict__ Kbuf, ushort* __restrict__ Qbuf)
{
    int idx = blockIdx.x * 256 + threadIdx.x;
    int i = idx >> 10, n = idx & 1023;
    float4 r = *(const float4*)&rot[i * 4];
    float4 w = *(const float4*)&Wrot[n * 4];
    float v = r.x * w.x + r.y * w.y + r.z * w.z + r.w * w.w;
    int h = 16 + (n >> 7), cc = n & 127;
    ushort u = f2h(v);
    if (cc < 64) Kbuf[(h * S_LEN + i) * CDIM + cc] = u;
    else         Qbuf[(h * S_LEN + i) * CDIM + cc - 64] = u;
}

__global__ __launch_bounds__(256) void zero_kernel(float* __restrict__ p) {
    p[blockIdx.x * 256 + threadIdx.x] = 0.f;
}

// Flash attention per (head, 64-row i-tile). 4 waves, d-split PV.
// S^T orientation QK (A=Q, B=K): lane's 16 scores all belong to row i=c ->
// scalar softmax state, 2-round shfl reduction, packed b64 P-writes.
// Double-buffered Q + P, one __syncthreads per iter. Writes directly to out.
// NOTE: no min-waves clause — R15's (256,4) forced VGPR=64 -> 0.5 GB scratch
// spill traffic (WRITE_SIZE 49->356 MB). Default lets allocator use ~120.
__global__ __launch_bounds__(256) void flash_kernel(
    const ushort* __restrict__ Kbuf, const ushort* __restrict__ Qbuf,
    const ushort* __restrict__ Vt, float* __restrict__ out)
{
    __shared__ ushort Qlds[2][64 * 72];   // [buf][j'][c], stride 72
    __shared__ ushort Plds[2][64 * 72];   // [buf][i'][j'], stride 72
    __shared__ float  Alds[2][64];        // [buf][i'] alpha / final 1/l

    const int tid = threadIdx.x;
    const int wave = tid >> 6, lane = tid & 63;
    const int g = lane >> 4, c = lane & 15;
    const int h = blockIdx.y;
    const int i0 = blockIdx.x * 64;
    const float SC = 0.51006973f;         // log2(e)/sqrt(8)

    // K b-frags for wave's 16 rows (i = i0 + wave*16 + c)
    const ushort* Krow = &Kbuf[(h * S_LEN + i0 + wave * 16 + c) * CDIM + g * 8];
    f16x8 ka0 = *(const f16x8*)Krow;
    f16x8 ka1 = *(const f16x8*)(Krow + 32);

    // V base for this wave's d-slice
    const ushort* Vbase = &Vt[(h * DDIM + wave * 64 + c) * S_LEN + g * 8];

    // Q staging indices
    const int qi0 = tid, qi1 = tid + 256;
    const int qr0 = qi0 >> 3, qc0 = (qi0 & 7) * 8;
    const int qr1 = qi1 >> 3, qc1 = (qi1 & 7) * 8;

    *(int4*)&Qlds[0][qr0 * 72 + qc0] =
        *(const int4*)&Qbuf[(h * S_LEN + qr0) * CDIM + qc0];
    *(int4*)&Qlds[0][qr1 * 72 + qc1] =
        *(const int4*)&Qbuf[(h * S_LEN + qr1) * CDIM + qc1];
    __syncthreads();

    f32x4 acc[16];   // [b*4+t]: rows b*16+g*4+r, cols wave*64+t*16+c
#pragma unroll
    for (int t = 0; t < 16; t++) acc[t] = f32x4{0, 0, 0, 0};
    float mrow = -1e30f, lrow = 0.f;      // state for row i = c (per lane)

    for (int j0 = 0; j0 < S_LEN; j0 += 64) {
        const int cur = (j0 >> 6) & 1, nxt = cur ^ 1;

        // prefetch next Q tile into regs (OOB reads land in Vt -> safe)
        const int jn = j0 + 64;
        int4 qn0 = *(const int4*)&Qbuf[(h * S_LEN + jn + qr0) * CDIM + qc0];
        int4 qn1 = *(const int4*)&Qbuf[(h * S_LEN + jn + qr1) * CDIM + qc1];

        // V fragments for THIS iter
        f16x8 vf0[4], vf1[4];
#pragma unroll
        for (int t = 0; t < 4; t++) {
            const ushort* Vr = Vbase + (t * 16) * S_LEN + j0;
            vf0[t] = *(const f16x8*)Vr;
            vf1[t] = *(const f16x8*)(Vr + 32);
        }

        // QK (S^T): lane holds S[i=c][j = jc*16 + g*4 + r]
        f32x4 Sf[4];
#pragma unroll
        for (int jc = 0; jc < 4; jc++) {
            const ushort* Qr = &Qlds[cur][(jc * 16 + c) * 72 + g * 8];
            f16x8 qb0 = *(const f16x8*)Qr;
            f16x8 qb1 = *(const f16x8*)(Qr + 32);
            f32x4 s = {0, 0, 0, 0};
            s = __builtin_amdgcn_mfma_f32_16x16x32_f16(qb0, ka0, s, 0, 0, 0);
            s = __builtin_amdgcn_mfma_f32_16x16x32_f16(qb1, ka1, s, 0, 0, 0);
            Sf[jc] = s * SC;              // exp2 domain
        }

        // softmax for row i=c: reduce own 16 values, then across g
        float nm = -1e30f;
#pragma unroll
        for (int jc = 0; jc < 4; jc++)
            nm = fmaxf(nm, fmaxf(fmaxf(Sf[jc][0], Sf[jc][1]),
                                 fmaxf(Sf[jc][2], Sf[jc][3])));
        nm = fmaxf(nm, __shfl_xor(nm, 16));
        nm = fmaxf(nm, __shfl_xor(nm, 32));
        nm = fmaxf(nm, mrow);
        float alpha = exp2f(mrow - nm);

        float rs = 0.f;
#pragma unroll
        for (int jc = 0; jc < 4; jc++) {
            float p0 = exp2f(Sf[jc][0] - nm);
            float p1 = exp2f(Sf[jc][1] - nm);
            float p2 = exp2f(Sf[jc][2] - nm);
            float p3 = exp2f(Sf[jc][3] - nm);
            rs += (p0 + p1) + (p2 + p3);
            uint2 w;
            w.x = pkh(p0, p1);
            w.y = pkh(p2, p3);
            *(uint2*)&Plds[cur][(wave * 16 + c) * 72 + jc * 16 + g * 4] = w;
        }
        rs += __shfl_xor(rs, 16);
        rs += __shfl_xor(rs, 32);
        lrow = lrow * alpha + rs;
        mrow = nm;
        if (g == 0) Alds[cur][wave * 16 + c] = alpha;

        // stage next Q tile
        *(int4*)&Qlds[nxt][qr0 * 72 + qc0] = qn0;
        *(int4*)&Qlds[nxt][qr1 * 72 + qc1] = qn1;

        __syncthreads();   // P + alpha visible; Q[nxt] staged

        // rescale acc by per-row alpha (broadcast reads, vector mul)
#pragma unroll
        for (int b = 0; b < 4; b++) {
            f32x4 ab = *(const f32x4*)&Alds[cur][b * 16 + g * 4];
#pragma unroll
            for (int t = 0; t < 4; t++) acc[b * 4 + t] *= ab;
        }

        // PV: P(64x64) @ V(64x64-slice)
#pragma unroll
        for (int b = 0; b < 4; b++) {
            const ushort* Pr = &Plds[cur][(b * 16 + c) * 72 + g * 8];
            f16x8 pa0 = *(const f16x8*)Pr;
            f16x8 pa1 = *(const f16x8*)(Pr + 32);
#pragma unroll
            for (int t = 0; t < 4; t++) {
                acc[b * 4 + t] = __builtin_amdgcn_mfma_f32_16x16x32_f16(pa0, vf0[t], acc[b * 4 + t], 0, 0, 0);
                acc[b * 4 + t] = __builtin_amdgcn_mfma_f32_16x16x32_f16(pa1, vf1[t], acc[b * 4 + t], 0, 0, 0);
            }
        }
    }

    // publish 1/lrow, then scale + accumulate directly into out
    __syncthreads();
    if (g == 0) Alds[0][wave * 16 + c] = 1.0f / lrow;
    __syncthreads();
#pragma unroll
    for (int b = 0; b < 4; b++) {
        f32x4 lb = *(const f32x4*)&Alds[0][b * 16 + g * 4];
#pragma unroll
        for (int t = 0; t < 4; t++)
#pragma unroll
            for (int r = 0; r < 4; r++) {
                int i = i0 + b * 16 + g * 4 + r;
                int d = wave * 64 + t * 16 + c;
                atomicAdd(&out[i * DDIM + d], acc[b * 4 + t][r] * lb[r]);
            }
    }
}

extern "C" void kernel_launch(void* const* d_in, const int* in_sizes, int n_in,
                              void* d_out, int out_size, void* d_ws, size_t ws_size,
                              hipStream_t stream) {
    const float *nodes = 0, *aux = 0, *rot = 0, *W_nodes = 0, *b_nodes = 0,
                *W_aux = 0, *b_aux = 0, *W_rot = 0, *W_val = 0, *b_val = 0;
    int i1024[2] = {-1, -1};
    int n1024 = 0;
    for (int i = 0; i < n_in; ++i) {
        const float* p = (const float*)d_in[i];
        switch (in_sizes[i]) {
            case 524288:  nodes   = p; break;
            case 131072:  aux     = p; break;
            case 8192:    rot     = p; break;
            case 262144:  W_nodes = p; break;
            case 65536:   W_aux   = p; break;
            case 4096:    W_rot   = p; break;
            case 1572864: W_val   = p; break;
            case 6144:    b_val   = p; break;
            case 1024:    if (n1024 < 2) i1024[n1024] = i; n1024++; break;
            default: break;
        }
    }
    if (n1024 == 2) {
        b_nodes = (const float*)d_in[i1024[0]];
        b_aux   = (const float*)d_in[i1024[1]];
    }
    if (!nodes || !aux || !rot || !W_nodes || !b_nodes || !W_aux || !b_aux ||
        !W_rot || !W_val || !b_val) {
        nodes   = (const float*)d_in[0];
        aux     = (const float*)d_in[1];
        rot     = (const float*)d_in[2];
        W_nodes = (const float*)d_in[3];
        b_nodes = (const float*)d_in[4];
        W_aux   = (const float*)d_in[5];
        b_aux   = (const float*)d_in[6];
        W_rot   = (const float*)d_in[7];
        W_val   = (const float*)d_in[8];
        b_val   = (const float*)d_in[9];
    }
    float* out = (float*)d_out;

    // ws layout: (unused f32 pad 2MB) | K f16 | Q f16 | Vt f16
    float*  Opad = (float*)d_ws;
    ushort* Kbuf = (ushort*)(Opad + S_LEN * DDIM);
    ushort* Qbuf = Kbuf + NHEAD * S_LEN * CDIM;
    ushort* Vt   = Qbuf + NHEAD * S_LEN * CDIM;

    dim3 blk(256);
    zero_kernel<<<dim3(S_LEN * DDIM / 256), blk, 0, stream>>>(out);
    gemm_bt_kernel<<<dim3(16, 32), blk, 0, stream>>>(nodes, W_nodes, b_nodes,
        2048, 1024, 256, 0, 0, Kbuf, Qbuf, nullptr);
    gemm_bt_kernel<<<dim3(16, 32), blk, 0, stream>>>(aux, W_aux, b_aux,
        2048, 1024, 64, 0, 8, Kbuf, Qbuf, nullptr);
    rot_proj_kernel<<<dim3(8192), blk, 0, stream>>>(rot, W_rot, Kbuf, Qbuf);
    gemm_bt_kernel<<<dim3(96, 32), blk, 0, stream>>>(nodes, W_val, b_val,
        2048, 6144, 256, 1, 0, nullptr, nullptr, Vt);
    flash_kernel<<<dim3(32, NHEAD), blk, 0, stream>>>(Kbuf, Qbuf, Vt, out);
}

// Round 17
// 256.473 us; speedup vs baseline: 1.4201x; 1.0604x over previous
//
#include <hip/hip_runtime.h>

#define S_LEN 2048
#define NHEAD 24
#define CDIM 64
#define DDIM 256

typedef _Float16 f16x8 __attribute__((ext_vector_type(8)));
typedef float f32x4 __attribute__((ext_vector_type(4)));

__device__ __forceinline__ ushort f2h(float f) {
    _Float16 h = (_Float16)f;
    return __builtin_bit_cast(ushort, h);
}
__device__ __forceinline__ uint pkh(float a, float b) {
    auto v = __builtin_amdgcn_cvt_pkrtz(a, b);   // __fp16 ext_vector(2)
    return __builtin_bit_cast(uint, v);
}
__device__ __forceinline__ uint pk2(float a, float b) {   // RTN pack (epilogue)
    return (uint)f2h(a) | ((uint)f2h(b) << 16);
}

// pack 8 consecutive f32 -> 8 f16 (register ops only)
__device__ __forceinline__ int4 cvt8(const float* __restrict__ p) {
    float4 a = *(const float4*)p;
    float4 b = *(const float4*)(p + 4);
    f16x8 h;
    h[0] = (_Float16)a.x; h[1] = (_Float16)a.y;
    h[2] = (_Float16)a.z; h[3] = (_Float16)a.w;
    h[4] = (_Float16)b.x; h[5] = (_Float16)b.y;
    h[6] = (_Float16)b.z; h[7] = (_Float16)b.w;
    return __builtin_bit_cast(int4, h);
}

// f32 -> f16 bulk convert, 8 elems/thread
__global__ __launch_bounds__(256) void cvt16_kernel(
    const float* __restrict__ src, ushort* __restrict__ dst, int n8)
{
    int idx = blockIdx.x * 256 + threadIdx.x;
    if (idx < n8) *(int4*)&dst[idx * 8] = cvt8(&src[idx * 8]);
}

// 128x128-tile GEMM, BK=64, f16 inputs: C = A16 · W16^T + bias -> Vt ([h][d][j], f16).
// 4 waves in 2x2; per wave 4x4 acc tiles of 16x16; 32 MFMA per K-iter.
// LDS rows padded to 72 ushorts (2-way banks = free). Packed 8B epilogue stores.
__global__ __launch_bounds__(256) void gemm128_kernel(
    const ushort* __restrict__ A16, const ushort* __restrict__ W16,
    const float* __restrict__ bias, int K, ushort* __restrict__ Vt)
{
    __shared__ ushort Asub[128 * 72];
    __shared__ ushort Wsub[128 * 72];
    const int tid = threadIdx.x;
    const int wave = tid >> 6, lane = tid & 63;
    const int g = lane >> 4, c = lane & 15;
    const int wm = wave & 1, wn = wave >> 1;
    const int m0 = blockIdx.y * 128, n0 = blockIdx.x * 128;

    f32x4 acc[16];
#pragma unroll
    for (int t = 0; t < 16; t++) acc[t] = f32x4{0, 0, 0, 0};

    for (int k0 = 0; k0 < K; k0 += 64) {
        __syncthreads();
#pragma unroll
        for (int q = 0; q < 4; q++) {
            int i = tid + 256 * q;               // 0..1023
            int row = i >> 3, kc = (i & 7) * 8;
            *(int4*)&Asub[row * 72 + kc] = *(const int4*)&A16[(m0 + row) * K + k0 + kc];
            *(int4*)&Wsub[row * 72 + kc] = *(const int4*)&W16[(n0 + row) * K + k0 + kc];
        }
        __syncthreads();

        f16x8 af0[4], af1[4];
#pragma unroll
        for (int mt = 0; mt < 4; mt++) {
            const ushort* Ar = &Asub[(wm * 64 + mt * 16 + c) * 72 + g * 8];
            af0[mt] = *(const f16x8*)Ar;
            af1[mt] = *(const f16x8*)(Ar + 32);
        }
#pragma unroll
        for (int nt = 0; nt < 4; nt++) {
            const ushort* Wr = &Wsub[(wn * 64 + nt * 16 + c) * 72 + g * 8];
            f16x8 bf0 = *(const f16x8*)Wr;
            f16x8 bf1 = *(const f16x8*)(Wr + 32);
#pragma unroll
            for (int mt = 0; mt < 4; mt++) {
                acc[mt * 4 + nt] = __builtin_amdgcn_mfma_f32_16x16x32_f16(af0[mt], bf0, acc[mt * 4 + nt], 0, 0, 0);
                acc[mt * 4 + nt] = __builtin_amdgcn_mfma_f32_16x16x32_f16(af1[mt], bf1, acc[mt * 4 + nt], 0, 0, 0);
            }
        }
    }

    // epilogue: n -> (h, d); 4 consecutive m per lane -> one 8B store
#pragma unroll
    for (int nt = 0; nt < 4; nt++) {
        int n = n0 + wn * 64 + nt * 16 + c;
        float bv = bias[n];
        int h = n >> 8, d = n & 255;
#pragma unroll
        for (int mt = 0; mt < 4; mt++) {
            int m = m0 + wm * 64 + mt * 16 + g * 4;
            f32x4 v = acc[mt * 4 + nt];
            uint2 pw;
            pw.x = pk2(v[0] + bv, v[1] + bv);
            pw.y = pk2(v[2] + bv, v[3] + bv);
            *(uint2*)&Vt[(h * DDIM + d) * S_LEN + m] = pw;
        }
    }
}

// C = A (MxK,f32) @ W^T (NxK,f32) + bias, MFMA f16 16x16x32, 64x64 tile (kq path).
__global__ __launch_bounds__(256) void gemm_bt_kernel(
    const float* __restrict__ A, const float* __restrict__ W,
    const float* __restrict__ bias, int M, int N, int K,
    int hbase,
    ushort* __restrict__ Kbuf, ushort* __restrict__ Qbuf)
{
    __shared__ ushort Asub[64 * 40];
    __shared__ ushort Wsub[64 * 40];
    const int tid = threadIdx.x;
    const int wave = tid >> 6, lane = tid & 63;
    const int g = lane >> 4, c = lane & 15;
    const int m0 = blockIdx.y * 64, n0 = blockIdx.x * 64;
    const int srow = tid >> 2;
    const int skk = (tid & 3) * 8;

    f32x4 acc[4] = {f32x4{0,0,0,0}, f32x4{0,0,0,0}, f32x4{0,0,0,0}, f32x4{0,0,0,0}};

    for (int k0 = 0; k0 < K; k0 += 32) {
        __syncthreads();
        *(int4*)&Asub[srow * 40 + skk] = cvt8(&A[(m0 + srow) * K + k0 + skk]);
        *(int4*)&Wsub[srow * 40 + skk] = cvt8(&W[(n0 + srow) * K + k0 + skk]);
        __syncthreads();
        f16x8 af = *(const f16x8*)&Asub[(wave * 16 + c) * 40 + g * 8];
#pragma unroll
        for (int t = 0; t < 4; t++) {
            f16x8 bf = *(const f16x8*)&Wsub[(t * 16 + c) * 40 + g * 8];
            acc[t] = __builtin_amdgcn_mfma_f32_16x16x32_f16(af, bf, acc[t], 0, 0, 0);
        }
    }

#pragma unroll
    for (int t = 0; t < 4; t++) {
        int n = n0 + t * 16 + c;
        float bv = bias[n];
#pragma unroll
        for (int r = 0; r < 4; r++) {
            int m = m0 + wave * 16 + g * 4 + r;
            ushort u = f2h(acc[t][r] + bv);
            int h = hbase + (n >> 7);
            int cc = n & 127;
            if (cc < 64) Kbuf[(h * S_LEN + m) * CDIM + cc] = u;
            else         Qbuf[(h * S_LEN + m) * CDIM + cc - 64] = u;
        }
    }
}

// rot projection: K=4, no bias, f32 math.
__global__ __launch_bounds__(256) void rot_proj_kernel(
    const float* __restrict__ rot, const float* __restrict__ Wrot,
    ushort* __restrict__ Kbuf, ushort* __restrict__ Qbuf)
{
    int idx = blockIdx.x * 256 + threadIdx.x;
    int i = idx >> 10, n = idx & 1023;
    float4 r = *(const float4*)&rot[i * 4];
    float4 w = *(const float4*)&Wrot[n * 4];
    float v = r.x * w.x + r.y * w.y + r.z * w.z + r.w * w.w;
    int h = 16 + (n >> 7), cc = n & 127;
    ushort u = f2h(v);
    if (cc < 64) Kbuf[(h * S_LEN + i) * CDIM + cc] = u;
    else         Qbuf[(h * S_LEN + i) * CDIM + cc - 64] = u;
}

__global__ __launch_bounds__(256) void zero_kernel(float* __restrict__ p) {
    p[blockIdx.x * 256 + threadIdx.x] = 0.f;
}

// Flash attention (R16 version, frozen): S^T QK, scalar softmax state, d-split PV.
__global__ __launch_bounds__(256) void flash_kernel(
    const ushort* __restrict__ Kbuf, const ushort* __restrict__ Qbuf,
    const ushort* __restrict__ Vt, float* __restrict__ out)
{
    __shared__ ushort Qlds[2][64 * 72];
    __shared__ ushort Plds[2][64 * 72];
    __shared__ float  Alds[2][64];

    const int tid = threadIdx.x;
    const int wave = tid >> 6, lane = tid & 63;
    const int g = lane >> 4, c = lane & 15;
    const int h = blockIdx.y;
    const int i0 = blockIdx.x * 64;
    const float SC = 0.51006973f;         // log2(e)/sqrt(8)

    const ushort* Krow = &Kbuf[(h * S_LEN + i0 + wave * 16 + c) * CDIM + g * 8];
    f16x8 ka0 = *(const f16x8*)Krow;
    f16x8 ka1 = *(const f16x8*)(Krow + 32);

    const ushort* Vbase = &Vt[(h * DDIM + wave * 64 + c) * S_LEN + g * 8];

    const int qi0 = tid, qi1 = tid + 256;
    const int qr0 = qi0 >> 3, qc0 = (qi0 & 7) * 8;
    const int qr1 = qi1 >> 3, qc1 = (qi1 & 7) * 8;

    *(int4*)&Qlds[0][qr0 * 72 + qc0] =
        *(const int4*)&Qbuf[(h * S_LEN + qr0) * CDIM + qc0];
    *(int4*)&Qlds[0][qr1 * 72 + qc1] =
        *(const int4*)&Qbuf[(h * S_LEN + qr1) * CDIM + qc1];
    __syncthreads();

    f32x4 acc[16];
#pragma unroll
    for (int t = 0; t < 16; t++) acc[t] = f32x4{0, 0, 0, 0};
    float mrow = -1e30f, lrow = 0.f;

    for (int j0 = 0; j0 < S_LEN; j0 += 64) {
        const int cur = (j0 >> 6) & 1, nxt = cur ^ 1;

        const int jn = j0 + 64;
        int4 qn0 = *(const int4*)&Qbuf[(h * S_LEN + jn + qr0) * CDIM + qc0];
        int4 qn1 = *(const int4*)&Qbuf[(h * S_LEN + jn + qr1) * CDIM + qc1];

        f16x8 vf0[4], vf1[4];
#pragma unroll
        for (int t = 0; t < 4; t++) {
            const ushort* Vr = Vbase + (t * 16) * S_LEN + j0;
            vf0[t] = *(const f16x8*)Vr;
            vf1[t] = *(const f16x8*)(Vr + 32);
        }

        f32x4 Sf[4];
#pragma unroll
        for (int jc = 0; jc < 4; jc++) {
            const ushort* Qr = &Qlds[cur][(jc * 16 + c) * 72 + g * 8];
            f16x8 qb0 = *(const f16x8*)Qr;
            f16x8 qb1 = *(const f16x8*)(Qr + 32);
            f32x4 s = {0, 0, 0, 0};
            s = __builtin_amdgcn_mfma_f32_16x16x32_f16(qb0, ka0, s, 0, 0, 0);
            s = __builtin_amdgcn_mfma_f32_16x16x32_f16(qb1, ka1, s, 0, 0, 0);
            Sf[jc] = s * SC;
        }

        float nm = -1e30f;
#pragma unroll
        for (int jc = 0; jc < 4; jc++)
            nm = fmaxf(nm, fmaxf(fmaxf(Sf[jc][0], Sf[jc][1]),
                                 fmaxf(Sf[jc][2], Sf[jc][3])));
        nm = fmaxf(nm, __shfl_xor(nm, 16));
        nm = fmaxf(nm, __shfl_xor(nm, 32));
        nm = fmaxf(nm, mrow);
        float alpha = exp2f(mrow - nm);

        float rs = 0.f;
#pragma unroll
        for (int jc = 0; jc < 4; jc++) {
            float p0 = exp2f(Sf[jc][0] - nm);
            float p1 = exp2f(Sf[jc][1] - nm);
            float p2 = exp2f(Sf[jc][2] - nm);
            float p3 = exp2f(Sf[jc][3] - nm);
            rs += (p0 + p1) + (p2 + p3);
            uint2 w;
            w.x = pkh(p0, p1);
            w.y = pkh(p2, p3);
            *(uint2*)&Plds[cur][(wave * 16 + c) * 72 + jc * 16 + g * 4] = w;
        }
        rs += __shfl_xor(rs, 16);
        rs += __shfl_xor(rs, 32);
        lrow = lrow * alpha + rs;
        mrow = nm;
        if (g == 0) Alds[cur][wave * 16 + c] = alpha;

        *(int4*)&Qlds[nxt][qr0 * 72 + qc0] = qn0;
        *(int4*)&Qlds[nxt][qr1 * 72 + qc1] = qn1;

        __syncthreads();

#pragma unroll
        for (int b = 0; b < 4; b++) {
            f32x4 ab = *(const f32x4*)&Alds[cur][b * 16 + g * 4];
#pragma unroll
            for (int t = 0; t < 4; t++) acc[b * 4 + t] *= ab;
        }

#pragma unroll
        for (int b = 0; b < 4; b++) {
            const ushort* Pr = &Plds[cur][(b * 16 + c) * 72 + g * 8];
            f16x8 pa0 = *(const f16x8*)Pr;
            f16x8 pa1 = *(const f16x8*)(Pr + 32);
#pragma unroll
            for (int t = 0; t < 4; t++) {
                acc[b * 4 + t] = __builtin_amdgcn_mfma_f32_16x16x32_f16(pa0, vf0[t], acc[b * 4 + t], 0, 0, 0);
                acc[b * 4 + t] = __builtin_amdgcn_mfma_f32_16x16x32_f16(pa1, vf1[t], acc[b * 4 + t], 0, 0, 0);
            }
        }
    }

    __syncthreads();
    if (g == 0) Alds[0][wave * 16 + c] = 1.0f / lrow;
    __syncthreads();
#pragma unroll
    for (int b = 0; b < 4; b++) {
        f32x4 lb = *(const f32x4*)&Alds[0][b * 16 + g * 4];
#pragma unroll
        for (int t = 0; t < 4; t++)
#pragma unroll
            for (int r = 0; r < 4; r++) {
                int i = i0 + b * 16 + g * 4 + r;
                int d = wave * 64 + t * 16 + c;
                atomicAdd(&out[i * DDIM + d], acc[b * 4 + t][r] * lb[r]);
            }
    }
}

extern "C" void kernel_launch(void* const* d_in, const int* in_sizes, int n_in,
                              void* d_out, int out_size, void* d_ws, size_t ws_size,
                              hipStream_t stream) {
    const float *nodes = 0, *aux = 0, *rot = 0, *W_nodes = 0, *b_nodes = 0,
                *W_aux = 0, *b_aux = 0, *W_rot = 0, *W_val = 0, *b_val = 0;
    int i1024[2] = {-1, -1};
    int n1024 = 0;
    for (int i = 0; i < n_in; ++i) {
        const float* p = (const float*)d_in[i];
        switch (in_sizes[i]) {
            case 524288:  nodes   = p; break;
            case 131072:  aux     = p; break;
            case 8192:    rot     = p; break;
            case 262144:  W_nodes = p; break;
            case 65536:   W_aux   = p; break;
            case 4096:    W_rot   = p; break;
            case 1572864: W_val   = p; break;
            case 6144:    b_val   = p; break;
            case 1024:    if (n1024 < 2) i1024[n1024] = i; n1024++; break;
            default: break;
        }
    }
    if (n1024 == 2) {
        b_nodes = (const float*)d_in[i1024[0]];
        b_aux   = (const float*)d_in[i1024[1]];
    }
    if (!nodes || !aux || !rot || !W_nodes || !b_nodes || !W_aux || !b_aux ||
        !W_rot || !W_val || !b_val) {
        nodes   = (const float*)d_in[0];
        aux     = (const float*)d_in[1];
        rot     = (const float*)d_in[2];
        W_nodes = (const float*)d_in[3];
        b_nodes = (const float*)d_in[4];
        W_aux   = (const float*)d_in[5];
        b_aux   = (const float*)d_in[6];
        W_rot   = (const float*)d_in[7];
        W_val   = (const float*)d_in[8];
        b_val   = (const float*)d_in[9];
    }
    float* out = (float*)d_out;

    // ws: pad 2MB | K f16 | Q f16 | Vt f16 | nodes16 (1MB) | Wval16 (3MB)
    float*  Opad = (float*)d_ws;
    ushort* Kbuf = (ushort*)(Opad + S_LEN * DDIM);
    ushort* Qbuf = Kbuf + NHEAD * S_LEN * CDIM;
    ushort* Vt   = Qbuf + NHEAD * S_LEN * CDIM;
    ushort* nodes16 = Vt + NHEAD * DDIM * S_LEN;
    ushort* Wval16  = nodes16 + 524288;

    dim3 blk(256);
    zero_kernel<<<dim3(S_LEN * DDIM / 256), blk, 0, stream>>>(out);
    // f32 -> f16 copies for the big GEMM
    cvt16_kernel<<<dim3(256), blk, 0, stream>>>(nodes, nodes16, 524288 / 8);
    cvt16_kernel<<<dim3(768), blk, 0, stream>>>(W_val, Wval16, 1572864 / 8);
    // kq projections (64x64 f32 path)
    gemm_bt_kernel<<<dim3(16, 32), blk, 0, stream>>>(nodes, W_nodes, b_nodes,
        2048, 1024, 256, 0, Kbuf, Qbuf);
    gemm_bt_kernel<<<dim3(16, 32), blk, 0, stream>>>(aux, W_aux, b_aux,
        2048, 1024, 64, 8, Kbuf, Qbuf);
    rot_proj_kernel<<<dim3(8192), blk, 0, stream>>>(rot, W_rot, Kbuf, Qbuf);
    // values: 128x128-tile f16 GEMM -> Vt
    gemm128_kernel<<<dim3(48, 16), blk, 0, stream>>>(nodes16, Wval16, b_val,
        256, Vt);
    // attention
    flash_kernel<<<dim3(32, NHEAD), blk, 0, stream>>>(Kbuf, Qbuf, Vt, out);
}

// Round 18
// 253.548 us; speedup vs baseline: 1.4365x; 1.0115x over previous
//
#include <hip/hip_runtime.h>

#define S_LEN 2048
#define NHEAD 24
#define CDIM 64
#define DDIM 256

typedef _Float16 f16x8 __attribute__((ext_vector_type(8)));
typedef float f32x4 __attribute__((ext_vector_type(4)));

__device__ __forceinline__ ushort f2h(float f) {
    _Float16 h = (_Float16)f;
    return __builtin_bit_cast(ushort, h);
}
__device__ __forceinline__ uint pkh(float a, float b) {
    auto v = __builtin_amdgcn_cvt_pkrtz(a, b);   // __fp16 ext_vector(2)
    return __builtin_bit_cast(uint, v);
}
__device__ __forceinline__ uint pk2(float a, float b) {   // RTN pack (epilogue)
    return (uint)f2h(a) | ((uint)f2h(b) << 16);
}

// pack 8 consecutive f32 -> 8 f16 (register ops only)
__device__ __forceinline__ int4 cvt8(const float* __restrict__ p) {
    float4 a = *(const float4*)p;
    float4 b = *(const float4*)(p + 4);
    f16x8 h;
    h[0] = (_Float16)a.x; h[1] = (_Float16)a.y;
    h[2] = (_Float16)a.z; h[3] = (_Float16)a.w;
    h[4] = (_Float16)b.x; h[5] = (_Float16)b.y;
    h[6] = (_Float16)b.z; h[7] = (_Float16)b.w;
    return __builtin_bit_cast(int4, h);
}

// Fused prep: zero out (131072 float4) | nodes->f16 (65536 int4) | W_val->f16 (196608 int4)
__global__ __launch_bounds__(256) void prep_kernel(
    const float* __restrict__ nodes, const float* __restrict__ W_val,
    float* __restrict__ out, ushort* __restrict__ nodes16, ushort* __restrict__ Wval16)
{
    int idx = blockIdx.x * 256 + threadIdx.x;
    if (idx < 131072) {
        ((float4*)out)[idx] = float4{0.f, 0.f, 0.f, 0.f};
    } else if (idx < 196608) {
        int i = idx - 131072;
        *(int4*)&nodes16[i * 8] = cvt8(&nodes[i * 8]);
    } else {
        int i = idx - 196608;
        *(int4*)&Wval16[i * 8] = cvt8(&W_val[i * 8]);
    }
}

// Fused projections. Block ranges:
//   [0,768):    gemm128 val: nodes16·Wval16^T + b_val -> Vt  (48 x 16 tiles)
//   [768,1792): kq 64x64 gemm: nodes (512 blocks) then aux (512 blocks)
//   [1792,2816): rot projection, 8 elems/thread
__global__ __launch_bounds__(256) void proj_kernel(
    const float* __restrict__ nodes, const float* __restrict__ W_nodes,
    const float* __restrict__ b_nodes,
    const float* __restrict__ aux, const float* __restrict__ W_aux,
    const float* __restrict__ b_aux,
    const float* __restrict__ rot, const float* __restrict__ W_rot,
    const ushort* __restrict__ nodes16, const ushort* __restrict__ Wval16,
    const float* __restrict__ b_val,
    ushort* __restrict__ Kbuf, ushort* __restrict__ Qbuf, ushort* __restrict__ Vt)
{
    __shared__ ushort Asub[128 * 72];
    __shared__ ushort Wsub[128 * 72];
    const int blk = blockIdx.x;
    const int tid = threadIdx.x;
    const int wave = tid >> 6, lane = tid & 63;
    const int g = lane >> 4, c = lane & 15;

    if (blk < 768) {
        // ---- 128x128-tile GEMM, BK=64, f16: Vt[h][d][j]
        const int wm = wave & 1, wn = wave >> 1;
        const int m0 = (blk / 48) * 128, n0 = (blk % 48) * 128;
        const int K = 256;

        f32x4 acc[16];
#pragma unroll
        for (int t = 0; t < 16; t++) acc[t] = f32x4{0, 0, 0, 0};

        for (int k0 = 0; k0 < K; k0 += 64) {
            __syncthreads();
#pragma unroll
            for (int q = 0; q < 4; q++) {
                int i = tid + 256 * q;
                int row = i >> 3, kc = (i & 7) * 8;
                *(int4*)&Asub[row * 72 + kc] = *(const int4*)&nodes16[(m0 + row) * K + k0 + kc];
                *(int4*)&Wsub[row * 72 + kc] = *(const int4*)&Wval16[(n0 + row) * K + k0 + kc];
            }
            __syncthreads();

            f16x8 af0[4], af1[4];
#pragma unroll
            for (int mt = 0; mt < 4; mt++) {
                const ushort* Ar = &Asub[(wm * 64 + mt * 16 + c) * 72 + g * 8];
                af0[mt] = *(const f16x8*)Ar;
                af1[mt] = *(const f16x8*)(Ar + 32);
            }
#pragma unroll
            for (int nt = 0; nt < 4; nt++) {
                const ushort* Wr = &Wsub[(wn * 64 + nt * 16 + c) * 72 + g * 8];
                f16x8 bf0 = *(const f16x8*)Wr;
                f16x8 bf1 = *(const f16x8*)(Wr + 32);
#pragma unroll
                for (int mt = 0; mt < 4; mt++) {
                    acc[mt * 4 + nt] = __builtin_amdgcn_mfma_f32_16x16x32_f16(af0[mt], bf0, acc[mt * 4 + nt], 0, 0, 0);
                    acc[mt * 4 + nt] = __builtin_amdgcn_mfma_f32_16x16x32_f16(af1[mt], bf1, acc[mt * 4 + nt], 0, 0, 0);
                }
            }
        }

#pragma unroll
        for (int nt = 0; nt < 4; nt++) {
            int n = n0 + wn * 64 + nt * 16 + c;
            float bv = b_val[n];
            int h = n >> 8, d = n & 255;
#pragma unroll
            for (int mt = 0; mt < 4; mt++) {
                int m = m0 + wm * 64 + mt * 16 + g * 4;
                f32x4 v = acc[mt * 4 + nt];
                uint2 pw;
                pw.x = pk2(v[0] + bv, v[1] + bv);
                pw.y = pk2(v[2] + bv, v[3] + bv);
                *(uint2*)&Vt[(h * DDIM + d) * S_LEN + m] = pw;
            }
        }
    } else if (blk < 1792) {
        // ---- kq 64x64 gemm (f32 inputs, cvt in staging)
        const int sub = blk - 768;
        const float *A, *W, *b;
        int K, hbase;
        if (sub < 512) { A = nodes; W = W_nodes; b = b_nodes; K = 256; hbase = 0; }
        else           { A = aux;   W = W_aux;   b = b_aux;   K = 64;  hbase = 8; }
        const int t5 = sub & 511;
        const int m0 = (t5 >> 4) * 64, n0 = (t5 & 15) * 64;
        const int srow = tid >> 2;
        const int skk = (tid & 3) * 8;

        f32x4 acc[4] = {f32x4{0,0,0,0}, f32x4{0,0,0,0}, f32x4{0,0,0,0}, f32x4{0,0,0,0}};

        for (int k0 = 0; k0 < K; k0 += 32) {
            __syncthreads();
            *(int4*)&Asub[srow * 40 + skk] = cvt8(&A[(m0 + srow) * K + k0 + skk]);
            *(int4*)&Wsub[srow * 40 + skk] = cvt8(&W[(n0 + srow) * K + k0 + skk]);
            __syncthreads();
            f16x8 af = *(const f16x8*)&Asub[(wave * 16 + c) * 40 + g * 8];
#pragma unroll
            for (int t = 0; t < 4; t++) {
                f16x8 bf = *(const f16x8*)&Wsub[(t * 16 + c) * 40 + g * 8];
                acc[t] = __builtin_amdgcn_mfma_f32_16x16x32_f16(af, bf, acc[t], 0, 0, 0);
            }
        }

#pragma unroll
        for (int t = 0; t < 4; t++) {
            int n = n0 + t * 16 + c;
            float bv = b[n];
#pragma unroll
            for (int r = 0; r < 4; r++) {
                int m = m0 + wave * 16 + g * 4 + r;
                ushort u = f2h(acc[t][r] + bv);
                int h = hbase + (n >> 7);
                int cc = n & 127;
                if (cc < 64) Kbuf[(h * S_LEN + m) * CDIM + cc] = u;
                else         Qbuf[(h * S_LEN + m) * CDIM + cc - 64] = u;
            }
        }
    } else {
        // ---- rot projection, 8 consecutive n per thread, vector store
        int u = (blk - 1792) * 256 + tid;    // 0..262143
        int i = u >> 7;                      // row 0..2047
        int n8 = (u & 127) * 8;              // base n, multiple of 8
        float4 r = *(const float4*)&rot[i * 4];
        ushort pv[8];
#pragma unroll
        for (int q = 0; q < 8; q++) {
            float4 w = *(const float4*)&W_rot[(n8 + q) * 4];
            pv[q] = f2h(r.x * w.x + r.y * w.y + r.z * w.z + r.w * w.w);
        }
        int h = 16 + (n8 >> 7), cc = n8 & 127;
        int4 pkt = *(int4*)pv;
        if (cc < 64) *(int4*)&Kbuf[(h * S_LEN + i) * CDIM + cc] = pkt;
        else         *(int4*)&Qbuf[(h * S_LEN + i) * CDIM + cc - 64] = pkt;
    }
}

// Flash attention (R16 version, frozen): S^T QK, scalar softmax state, d-split PV.
__global__ __launch_bounds__(256) void flash_kernel(
    const ushort* __restrict__ Kbuf, const ushort* __restrict__ Qbuf,
    const ushort* __restrict__ Vt, float* __restrict__ out)
{
    __shared__ ushort Qlds[2][64 * 72];
    __shared__ ushort Plds[2][64 * 72];
    __shared__ float  Alds[2][64];

    const int tid = threadIdx.x;
    const int wave = tid >> 6, lane = tid & 63;
    const int g = lane >> 4, c = lane & 15;
    const int h = blockIdx.y;
    const int i0 = blockIdx.x * 64;
    const float SC = 0.51006973f;         // log2(e)/sqrt(8)

    const ushort* Krow = &Kbuf[(h * S_LEN + i0 + wave * 16 + c) * CDIM + g * 8];
    f16x8 ka0 = *(const f16x8*)Krow;
    f16x8 ka1 = *(const f16x8*)(Krow + 32);

    const ushort* Vbase = &Vt[(h * DDIM + wave * 64 + c) * S_LEN + g * 8];

    const int qi0 = tid, qi1 = tid + 256;
    const int qr0 = qi0 >> 3, qc0 = (qi0 & 7) * 8;
    const int qr1 = qi1 >> 3, qc1 = (qi1 & 7) * 8;

    *(int4*)&Qlds[0][qr0 * 72 + qc0] =
        *(const int4*)&Qbuf[(h * S_LEN + qr0) * CDIM + qc0];
    *(int4*)&Qlds[0][qr1 * 72 + qc1] =
        *(const int4*)&Qbuf[(h * S_LEN + qr1) * CDIM + qc1];
    __syncthreads();

    f32x4 acc[16];
#pragma unroll
    for (int t = 0; t < 16; t++) acc[t] = f32x4{0, 0, 0, 0};
    float mrow = -1e30f, lrow = 0.f;

    for (int j0 = 0; j0 < S_LEN; j0 += 64) {
        const int cur = (j0 >> 6) & 1, nxt = cur ^ 1;

        const int jn = j0 + 64;
        int4 qn0 = *(const int4*)&Qbuf[(h * S_LEN + jn + qr0) * CDIM + qc0];
        int4 qn1 = *(const int4*)&Qbuf[(h * S_LEN + jn + qr1) * CDIM + qc1];

        f16x8 vf0[4], vf1[4];
#pragma unroll
        for (int t = 0; t < 4; t++) {
            const ushort* Vr = Vbase + (t * 16) * S_LEN + j0;
            vf0[t] = *(const f16x8*)Vr;
            vf1[t] = *(const f16x8*)(Vr + 32);
        }

        f32x4 Sf[4];
#pragma unroll
        for (int jc = 0; jc < 4; jc++) {
            const ushort* Qr = &Qlds[cur][(jc * 16 + c) * 72 + g * 8];
            f16x8 qb0 = *(const f16x8*)Qr;
            f16x8 qb1 = *(const f16x8*)(Qr + 32);
            f32x4 s = {0, 0, 0, 0};
            s = __builtin_amdgcn_mfma_f32_16x16x32_f16(qb0, ka0, s, 0, 0, 0);
            s = __builtin_amdgcn_mfma_f32_16x16x32_f16(qb1, ka1, s, 0, 0, 0);
            Sf[jc] = s * SC;
        }

        float nm = -1e30f;
#pragma unroll
        for (int jc = 0; jc < 4; jc++)
            nm = fmaxf(nm, fmaxf(fmaxf(Sf[jc][0], Sf[jc][1]),
                                 fmaxf(Sf[jc][2], Sf[jc][3])));
        nm = fmaxf(nm, __shfl_xor(nm, 16));
        nm = fmaxf(nm, __shfl_xor(nm, 32));
        nm = fmaxf(nm, mrow);
        float alpha = exp2f(mrow - nm);

        float rs = 0.f;
#pragma unroll
        for (int jc = 0; jc < 4; jc++) {
            float p0 = exp2f(Sf[jc][0] - nm);
            float p1 = exp2f(Sf[jc][1] - nm);
            float p2 = exp2f(Sf[jc][2] - nm);
            float p3 = exp2f(Sf[jc][3] - nm);
            rs += (p0 + p1) + (p2 + p3);
            uint2 w;
            w.x = pkh(p0, p1);
            w.y = pkh(p2, p3);
            *(uint2*)&Plds[cur][(wave * 16 + c) * 72 + jc * 16 + g * 4] = w;
        }
        rs += __shfl_xor(rs, 16);
        rs += __shfl_xor(rs, 32);
        lrow = lrow * alpha + rs;
        mrow = nm;
        if (g == 0) Alds[cur][wave * 16 + c] = alpha;

        *(int4*)&Qlds[nxt][qr0 * 72 + qc0] = qn0;
        *(int4*)&Qlds[nxt][qr1 * 72 + qc1] = qn1;

        __syncthreads();

#pragma unroll
        for (int b = 0; b < 4; b++) {
            f32x4 ab = *(const f32x4*)&Alds[cur][b * 16 + g * 4];
#pragma unroll
            for (int t = 0; t < 4; t++) acc[b * 4 + t] *= ab;
        }

#pragma unroll
        for (int b = 0; b < 4; b++) {
            const ushort* Pr = &Plds[cur][(b * 16 + c) * 72 + g * 8];
            f16x8 pa0 = *(const f16x8*)Pr;
            f16x8 pa1 = *(const f16x8*)(Pr + 32);
#pragma unroll
            for (int t = 0; t < 4; t++) {
                acc[b * 4 + t] = __builtin_amdgcn_mfma_f32_16x16x32_f16(pa0, vf0[t], acc[b * 4 + t], 0, 0, 0);
                acc[b * 4 + t] = __builtin_amdgcn_mfma_f32_16x16x32_f16(pa1, vf1[t], acc[b * 4 + t], 0, 0, 0);
            }
        }
    }

    __syncthreads();
    if (g == 0) Alds[0][wave * 16 + c] = 1.0f / lrow;
    __syncthreads();
#pragma unroll
    for (int b = 0; b < 4; b++) {
        f32x4 lb = *(const f32x4*)&Alds[0][b * 16 + g * 4];
#pragma unroll
        for (int t = 0; t < 4; t++)
#pragma unroll
            for (int r = 0; r < 4; r++) {
                int i = i0 + b * 16 + g * 4 + r;
                int d = wave * 64 + t * 16 + c;
                atomicAdd(&out[i * DDIM + d], acc[b * 4 + t][r] * lb[r]);
            }
    }
}

extern "C" void kernel_launch(void* const* d_in, const int* in_sizes, int n_in,
                              void* d_out, int out_size, void* d_ws, size_t ws_size,
                              hipStream_t stream) {
    const float *nodes = 0, *aux = 0, *rot = 0, *W_nodes = 0, *b_nodes = 0,
                *W_aux = 0, *b_aux = 0, *W_rot = 0, *W_val = 0, *b_val = 0;
    int i1024[2] = {-1, -1};
    int n1024 = 0;
    for (int i = 0; i < n_in; ++i) {
        const float* p = (const float*)d_in[i];
        switch (in_sizes[i]) {
            case 524288:  nodes   = p; break;
            case 131072:  aux     = p; break;
            case 8192:    rot     = p; break;
            case 262144:  W_nodes = p; break;
            case 65536:   W_aux   = p; break;
            case 4096:    W_rot   = p; break;
            case 1572864: W_val   = p; break;
            case 6144:    b_val   = p; break;
            case 1024:    if (n1024 < 2) i1024[n1024] = i; n1024++; break;
            default: break;
        }
    }
    if (n1024 == 2) {
        b_nodes = (const float*)d_in[i1024[0]];
        b_aux   = (const float*)d_in[i1024[1]];
    }
    if (!nodes || !aux || !rot || !W_nodes || !b_nodes || !W_aux || !b_aux ||
        !W_rot || !W_val || !b_val) {
        nodes   = (const float*)d_in[0];
        aux     = (const float*)d_in[1];
        rot     = (const float*)d_in[2];
        W_nodes = (const float*)d_in[3];
        b_nodes = (const float*)d_in[4];
        W_aux   = (const float*)d_in[5];
        b_aux   = (const float*)d_in[6];
        W_rot   = (const float*)d_in[7];
        W_val   = (const float*)d_in[8];
        b_val   = (const float*)d_in[9];
    }
    float* out = (float*)d_out;

    // ws: pad 2MB | K f16 | Q f16 | Vt f16 | nodes16 (1MB) | Wval16 (3MB)
    float*  Opad = (float*)d_ws;
    ushort* Kbuf = (ushort*)(Opad + S_LEN * DDIM);
    ushort* Qbuf = Kbuf + NHEAD * S_LEN * CDIM;
    ushort* Vt   = Qbuf + NHEAD * S_LEN * CDIM;
    ushort* nodes16 = Vt + NHEAD * DDIM * S_LEN;
    ushort* Wval16  = nodes16 + 524288;

    dim3 blk(256);
    prep_kernel<<<dim3(1536), blk, 0, stream>>>(nodes, W_val, out, nodes16, Wval16);
    proj_kernel<<<dim3(2816), blk, 0, stream>>>(
        nodes, W_nodes, b_nodes, aux, W_aux, b_aux, rot, W_rot,
        nodes16, Wval16, b_val, Kbuf, Qbuf, Vt);
    flash_kernel<<<dim3(32, NHEAD), blk, 0, stream>>>(Kbuf, Qbuf, Vt, out);
}